// Round 6
// baseline (1517.275 us; speedup 1.0000x reference)
//
#include <hip/hip_runtime.h>
#include <hip/hip_bf16.h>

// SSAMLayer: decompose GEMM (fp32) -> [xpose to f16 hi/lo] -> 4x conv3x3 via
// MFMA f16 3-product split -> attention tail (fp32) -> fused spline output.
// Conv v3: B-fragments loaded DIRECTLY from global (L2-resident W) with
// one-tap register prefetch; W LDS slabs + 72/80 barriers eliminated.
// LDS holds only the swizzled A tile (25.6KB main loop / 32KB epilogue).

#define CHW   1048576   // 256*64*64
#define HW    4096      // 64*64

typedef _Float16 f16;
typedef _Float16 f16x8 __attribute__((ext_vector_type(8)));
typedef float    f32x4 __attribute__((ext_vector_type(4)));

// ---------------------------------------------------------------------------
// K2[c][o], o = n*256+t : irfft-of-sliced-rfft as a per-pixel matrix.
// K_n[t][c] = (1/256)[cos(2pi*s*c/256) + 2*sum_{k=1}^{L-1} cos(2pi*((s+k)c - kt)/256)]
__global__ __launch_bounds__(256) void k2_kernel(float* __restrict__ K2) {
    __shared__ float ctab[256];
    const int c = blockIdx.x;
    const int t = threadIdx.x;
    ctab[t] = cosf((float)t * 0.024543692606170259f);  // 2*pi/256
    __syncthreads();
#pragma unroll
    for (int q = 0; q < 4; q++) {
        const int o = q * 256 + t;
        const int s = q * 32;
        const int L = (q == 3) ? 33 : 32;
        float sum = ctab[(s * c) & 255];
        for (int k = 1; k < L; k++) {
            int m = ((s + k) * c + k * (256 - t)) & 255;
            sum += 2.f * ctab[m];
        }
        K2[c * 1024 + o] = sum * 0.00390625f;
    }
}

// Split conv weights into f16 hi/lo, layout [tap][oc][ic].
__global__ __launch_bounds__(256) void wsplit_kernel(const float* __restrict__ w,
                                                     f16* __restrict__ Wh,
                                                     f16* __restrict__ Wl) {
    const int b = blockIdx.x;            // 0..2303
    const int tap = b >> 8, oc = b & 255;
    const int ic = threadIdx.x;
    const float v = w[(oc * 256 + ic) * 9 + tap];
    const f16 hi = (f16)v;
    Wh[b * 256 + ic] = hi;
    Wl[b * 256 + ic] = (f16)(v - (float)hi);
}

// w_eff[n][c] = sum_j spline_w[n][j][c]*scalers[n][j][c]; BN folded scale/bias.
__global__ __launch_bounds__(256) void small_pre_kernel(
    const float* __restrict__ spw, const float* __restrict__ scl,
    const float* __restrict__ bn_g, const float* __restrict__ bn_b,
    const float* __restrict__ bn_m, const float* __restrict__ bn_v,
    const float* __restrict__ ft_b1, float* __restrict__ weff,
    float* __restrict__ bnscale, float* __restrict__ bnbias) {
    const int c = threadIdx.x;
    const float s = bn_g[c] * rsqrtf(bn_v[c] + 1e-5f);
    bnscale[c] = s;
    bnbias[c] = (ft_b1[c] - bn_m[c]) * s + bn_b[c];
    for (int n = 0; n < 4; n++) {
        float acc = 0.f;
        for (int j = 0; j < 256; j++)
            acc += spw[n * 65536 + j * 256 + c] * scl[n * 65536 + j * 256 + c];
        weff[n * 256 + c] = acc;
    }
}

// xd[b][n][h][w][cc] = sum_c x[b][c][h][w] * K2[c][n*256+cc]   (fp32 GEMM)
__global__ __launch_bounds__(256) void decompose_kernel(const float* __restrict__ x,
                                                        const float* __restrict__ K2,
                                                        float* __restrict__ xd) {
    const int o0 = blockIdx.x * 128;
    const int p0 = blockIdx.y * 64;
    const int b = p0 >> 12;
    const int prow = p0 & 4095;
    const int t = threadIdx.x;
    const int pg = t >> 4, og = t & 15;
    __shared__ float As[16][64];
    __shared__ float Bs[16][128];
    float acc[4][8];
#pragma unroll
    for (int i = 0; i < 4; i++)
#pragma unroll
        for (int j = 0; j < 8; j++) acc[i][j] = 0.f;

    for (int c0 = 0; c0 < 256; c0 += 16) {
#pragma unroll
        for (int i = 0; i < 4; i++) {
            int c = (t >> 6) + i * 4;
            As[c][t & 63] = x[b * CHW + (c0 + c) * HW + prow + (t & 63)];
        }
#pragma unroll
        for (int i = 0; i < 8; i++) {
            int l = i * 256 + t;
            Bs[l >> 7][l & 127] = K2[(c0 + (l >> 7)) * 1024 + o0 + (l & 127)];
        }
        __syncthreads();
#pragma unroll
        for (int k = 0; k < 16; k++) {
            float a[4], bb[8];
            *(float4*)a = *(const float4*)&As[k][pg * 4];
            *(float4*)&bb[0] = *(const float4*)&Bs[k][og * 8];
            *(float4*)&bb[4] = *(const float4*)&Bs[k][og * 8 + 4];
#pragma unroll
            for (int i = 0; i < 4; i++)
#pragma unroll
                for (int j = 0; j < 8; j++) acc[i][j] = fmaf(a[i], bb[j], acc[i][j]);
        }
        __syncthreads();
    }
#pragma unroll
    for (int i = 0; i < 4; i++) {
        const int p = prow + pg * 4 + i;
#pragma unroll
        for (int j = 0; j < 8; j++) {
            const int o = o0 + og * 8 + j;
            const int n = o >> 8, cc = o & 255;
            xd[b * 4194304 + n * CHW + p * 256 + cc] = acc[i][j];
        }
    }
}

// Transpose decompose output (raw reinterpretation) into conv1's A layout:
// X[p'][c'] = bufA[c'*16 + (p'>>8)][p'&255]   (per bn), split f16 hi/lo.
__global__ __launch_bounds__(256) void xpose_kernel(const float* __restrict__ in,
                                                    f16* __restrict__ Xh,
                                                    f16* __restrict__ Xl) {
    const int bn = blockIdx.y;
    const int tid = blockIdx.x;            // 0..127
    const int k = tid & 15;
    const int cc0 = ((tid >> 4) & 1) * 128;
    const int c0p = (tid >> 5) * 64;       // c' tile base
    __shared__ float T[64 * 132];
    const int base = bn * 1048576;
    for (int c = threadIdx.x; c < 2048; c += 256) {   // 8 iters
        int cl = c >> 5;           // c' local 0..63
        int ccq = c & 31;          // cc chunk of 4
        int pd = (c0p + cl) * 16 + k;
        *(float4*)&T[cl * 132 + ccq * 4] =
            *(const float4*)&in[base + pd * 256 + cc0 + ccq * 4];
    }
    __syncthreads();
    for (int m = threadIdx.x; m < 1024; m += 256) {   // 4 iters
        int pl = m >> 3;           // 0..127
        int cq = m & 7;            // c' chunk of 8
        f16x8 hi, lo;
#pragma unroll
        for (int j = 0; j < 8; ++j) {
            float v = T[(cq * 8 + j) * 132 + pl];
            f16 h = (f16)v;
            hi[j] = h;
            lo[j] = (f16)(v - (float)h);
        }
        int pp = k * 256 + cc0 + pl;
        int o = base + pp * 256 + c0p + cq * 8;
        *(f16x8*)&Xh[o] = hi;
        *(f16x8*)&Xl[o] = lo;
    }
}

// ---------------------------------------------------------------------------
// Conv3x3 256->256 via MFMA f16 3-product split, v3 schedule.
// LDS: A tile only, [200 pos][2 half][32 ic], 128B rows, quad ^= pos&7.
// B-fragments: direct global loads (W is L2-resident, 4.5MB hi+lo),
// one-tap-ahead register prefetch in bh/bl[2][4] (parity ping-pong; tap0's
// loads issued at chunk top, hidden under A staging). 2 barriers per chunk.
template <int MODE, int PACKED>
__global__ __launch_bounds__(256, 2) void conv_mfma_kernel(
    const f16* __restrict__ Xh, const f16* __restrict__ Xl,
    const f16* __restrict__ Wg_h, const f16* __restrict__ Wg_l,
    const float* __restrict__ scale, const float* __restrict__ bias,
    f16* __restrict__ Oh, f16* __restrict__ Ol, float* __restrict__ Of) {
    const int oc0 = blockIdx.x * 128;
    const int h0 = (blockIdx.y >> 2) * 8;
    const int w0 = (blockIdx.y & 3) * 16;
    const int bn = blockIdx.z;

    __shared__ __align__(16) f16 smem[16384];   // 32 KB (A: 12800; epi: 16384)
    f16* At = smem;

    const int t = threadIdx.x;
    const int wid = t >> 6, lane = t & 63;
    const int wm = wid >> 1, wn = wid & 1;
    const int lrow = lane & 15, g = lane >> 4;

    // staging decomposition of thread id (16B chunk = 8 f16 of one half)
    const int row_s = t >> 3;            // 0..31 (+32 per iter)
    const int sub_s = t & 7;             // half*4 + icq
    const int half_s = sub_s >> 2, icq_s = sub_s & 3;
    const int swz_s = (sub_s ^ (row_s & 7)) << 3;   // invariant under row+32

    f32x4 acc[4][4];
    const f32x4 z4 = {0.f, 0.f, 0.f, 0.f};
#pragma unroll
    for (int i = 0; i < 4; i++)
#pragma unroll
        for (int j = 0; j < 4; j++) acc[i][j] = z4;

    const int xbase = bn * CHW;

    // per-lane W base: row = oc0 + wn*64 + lrow, element offset g*8
    const size_t wlane = (size_t)(oc0 + wn * 64 + lrow) * 256 + g * 8;
    const f16* wh_base = Wg_h + wlane;
    const f16* wl_base = Wg_l + wlane;

    f16x8 bh[2][4], bl[2][4];

#pragma unroll 1
    for (int chunk = 0; chunk < 8; ++chunk) {
        const int ic0 = chunk * 32;
        __syncthreads();   // prev-chunk readers done; safe to overwrite At
        // ---- issue tap0 B prefetch (hides under A staging) ----
#pragma unroll
        for (int nf = 0; nf < 4; ++nf) {
            bh[0][nf] = *(const f16x8*)(wh_base + nf * 4096 + ic0);
            bl[0][nf] = *(const f16x8*)(wl_base + nf * 4096 + ic0);
        }
        // ---- stage A: 1600 16B chunks, swizzled ----
        {
            const f16* xs = (half_s ? Xl : Xh) + xbase + ic0 + icq_s * 8;
#pragma unroll
            for (int i = 0; i < 7; ++i) {
                int c = t + i * 256;
                if (c < 1600) {
                    int pos = row_s + i * 32;
                    int r = pos / 20, col = pos - r * 20;
                    int gy = h0 - 1 + r, gx = w0 - 1 + col;
                    f16x8 v = {};
                    if (col < 18 && (unsigned)gy < 64u && (unsigned)gx < 64u)
                        v = *(const f16x8*)(xs + (gy * 64 + gx) * 256);
                    *(f16x8*)&At[pos * 64 + swz_s] = v;
                }
            }
        }
        __syncthreads();
#pragma unroll
        for (int tap = 0; tap < 9; ++tap) {
            const int ky = tap / 3, kx = tap % 3;
            const int pc = tap & 1;
            // ---- prefetch next tap's B frags (consumed next iteration) ----
            if (tap < 8) {
                const size_t wo = (size_t)(tap + 1) * 65536 + ic0;
#pragma unroll
                for (int nf = 0; nf < 4; ++nf) {
                    bh[pc ^ 1][nf] = *(const f16x8*)(wh_base + wo + nf * 4096);
                    bl[pc ^ 1][nf] = *(const f16x8*)(wl_base + wo + nf * 4096);
                }
            }
            // ---- A fragments (conflict-free swizzled reads) + MFMA ----
            f16x8 a_h[4], a_l[4];
#pragma unroll
            for (int mf = 0; mf < 4; ++mf) {
                int pos = (wm * 4 + mf + ky) * 20 + (lrow + kx);
                int p7 = (pos & 7) << 3;
                a_h[mf] = *(const f16x8*)&At[pos * 64 + ((g << 3) ^ p7)];
                a_l[mf] = *(const f16x8*)&At[pos * 64 + (((4 + g) << 3) ^ p7)];
            }
#pragma unroll
            for (int mf = 0; mf < 4; ++mf)
#pragma unroll
                for (int nf = 0; nf < 4; ++nf) {
                    acc[mf][nf] = __builtin_amdgcn_mfma_f32_16x16x32_f16(
                        a_h[mf], bh[pc][nf], acc[mf][nf], 0, 0, 0);
                    acc[mf][nf] = __builtin_amdgcn_mfma_f32_16x16x32_f16(
                        a_h[mf], bl[pc][nf], acc[mf][nf], 0, 0, 0);
                    acc[mf][nf] = __builtin_amdgcn_mfma_f32_16x16x32_f16(
                        a_l[mf], bh[pc][nf], acc[mf][nf], 0, 0, 0);
                }
        }
    }

    // ---- epilogue ----  D frag: col(oc) = lane&15, row(ow) = g*4 + reg
    if (PACKED == 0) {
#pragma unroll
        for (int nf = 0; nf < 4; ++nf) {
            const int oc = oc0 + wn * 64 + nf * 16 + lrow;
            const float sc = (MODE == 1) ? scale[oc] : 1.f;
            const float bi = bias[oc];
#pragma unroll
            for (int mf = 0; mf < 4; ++mf) {
                const int oh = wm * 4 + mf;
                float4 o;
                float* op = &o.x;
#pragma unroll
                for (int j = 0; j < 4; ++j) {
                    float v = acc[mf][nf][j];
                    op[j] = (MODE == 1) ? fmaxf(v * sc + bi, 0.f) : (v + bi);
                }
                *(float4*)&Of[bn * CHW + oc * HW + (h0 + oh) * 64 + w0 + g * 4] = o;
            }
        }
    } else {
        // Th/Tl: [128 px][64 oc] f16, 128B rows, same XOR swizzle.
        f16* Th = smem;
        f16* Tl = smem + 8192;
        for (int half = 0; half < 2; ++half) {
            __syncthreads();
            if (wn == half) {
#pragma unroll
                for (int nf = 0; nf < 4; ++nf) {
                    const int oclb = nf * 16 + lrow;      // 0..63 within half
                    const int oc = oc0 + half * 64 + oclb;
                    const float sc = (MODE == 1) ? scale[oc] : 1.f;
                    const float bi = bias[oc];
#pragma unroll
                    for (int mf = 0; mf < 4; ++mf) {
                        const int pb = (wm * 4 + mf) * 16;
#pragma unroll
                        for (int j = 0; j < 4; ++j) {
                            float v = acc[mf][nf][j];
                            v = (MODE == 1) ? fmaxf(v * sc + bi, 0.f) : (v + bi);
                            f16 hi = (f16)v;
                            int p = pb + g * 4 + j;
                            int idx = p * 64 + (oclb ^ ((p & 7) << 3));
                            Th[idx] = hi;
                            Tl[idx] = (f16)(v - (float)hi);
                        }
                    }
                }
            }
            __syncthreads();
            for (int c = t; c < 1024; c += 256) {
                int p = c >> 3, q = c & 7;
                int src = p * 64 + ((q ^ (p & 7)) << 3);
                int gp = xbase + ((h0 + (p >> 4)) * 64 + w0 + (p & 15)) * 256 +
                         oc0 + half * 64 + q * 8;
                *(f16x8*)&Oh[gp] = *(const f16x8*)&Th[src];
                *(f16x8*)&Ol[gp] = *(const f16x8*)&Tl[src];
            }
        }
    }
}

// ---------------------------------------------------------------------------
__global__ __launch_bounds__(256) void gap_kernel(const float* __restrict__ t2,
                                                  float* __restrict__ gap) {
    const int bc = blockIdx.x;
    const float* p = t2 + bc * HW;
    float s = 0.f;
    for (int i = threadIdx.x; i < 4096; i += 256) s += p[i];
    __shared__ float red[256];
    red[threadIdx.x] = s;
    __syncthreads();
    for (int off = 128; off > 0; off >>= 1) {
        if (threadIdx.x < off) red[threadIdx.x] += red[threadIdx.x + off];
        __syncthreads();
    }
    if (threadIdx.x == 0) gap[bc] = red[0] * (1.f / 4096.f);
}

__global__ __launch_bounds__(256) void ca_kernel(
    const float* __restrict__ gap, const float* __restrict__ w1,
    const float* __restrict__ b1, const float* __restrict__ w2,
    const float* __restrict__ b2, float* __restrict__ cw) {
    const int bn = blockIdx.x;
    const int t = threadIdx.x;
    __shared__ float gsh[256];
    __shared__ float hid[64];
    gsh[t] = gap[bn * 256 + t];
    __syncthreads();
    if (t < 64) {
        float a = b1[t];
        for (int c = 0; c < 256; c++) a += w1[t * 256 + c] * gsh[c];
        hid[t] = 0.5f * a * (1.f + erff(a * 0.70710678118654752f));
    }
    __syncthreads();
    float a = b2[t];
    for (int j = 0; j < 64; j++) a += w2[t * 64 + j] * hid[j];
    cw[bn * 256 + t] = 1.f / (1.f + expf(-a));
}

__global__ __launch_bounds__(256) void samap_kernel(const float* __restrict__ t2,
                                                    const float* __restrict__ cw,
                                                    float* __restrict__ avg,
                                                    float* __restrict__ mx) {
    const int bn = blockIdx.x >> 4;
    const int h = (blockIdx.x & 15) * 4 + (threadIdx.x >> 6);
    const int w = threadIdx.x & 63;
    const float* p = t2 + bn * CHW + h * 64 + w;
    float s = 0.f, m = -3.4e38f;
    for (int c = 0; c < 256; c++) {
        float v = p[c * HW] * cw[bn * 256 + c];
        s += v;
        m = fmaxf(m, v);
    }
    avg[bn * HW + h * 64 + w] = s * (1.f / 256.f);
    mx[bn * HW + h * 64 + w] = m;
}

__global__ __launch_bounds__(256) void sw_kernel(const float* __restrict__ avg,
                                                 const float* __restrict__ mx,
                                                 const float* __restrict__ saw,
                                                 const float* __restrict__ sab,
                                                 float* __restrict__ sw) {
    const int bn = blockIdx.x >> 4;
    const int h = (blockIdx.x & 15) * 4 + (threadIdx.x >> 6);
    const int w = threadIdx.x & 63;
    float a = sab[0];
#pragma unroll
    for (int ky = 0; ky < 3; ky++) {
        int y = h + ky - 1;
        if ((unsigned)y >= 64u) continue;
#pragma unroll
        for (int kx = 0; kx < 3; kx++) {
            int x = w + kx - 1;
            if ((unsigned)x >= 64u) continue;
            int idx = bn * HW + y * 64 + x;
            a += saw[ky * 3 + kx] * avg[idx] + saw[9 + ky * 3 + kx] * mx[idx];
        }
    }
    sw[bn * HW + h * 64 + w] = 1.f / (1.f + expf(-a));
}

__global__ __launch_bounds__(256) void fuse_kernel(const float* __restrict__ t2,
                                                   const float* __restrict__ cw,
                                                   const float* __restrict__ sw,
                                                   const float* __restrict__ weff,
                                                   float* __restrict__ out) {
    const int b = blockIdx.x >> 6;
    const int ho = blockIdx.x & 63;
    const int co = threadIdx.x;
    __shared__ float T[256 * 33];
    float we[4];
#pragma unroll
    for (int n = 0; n < 4; n++) we[n] = weff[n * 256 + co];

    for (int hf = 0; hf < 2; hf++) {
        for (int wo = 0; wo < 32; wo++) {
            const int o = ho * 16384 + (hf * 32 + wo) * 256 + co;
            const int ct = o >> 12;
            const int ht = (o >> 6) & 63;
            const int wt = o & 63;
            float acc = 0.f;
#pragma unroll
            for (int n = 0; n < 4; n++) {
                const int bn = b * 4 + n;
                acc += we[n] * t2[bn * CHW + o] * cw[bn * 256 + ct] *
                       sw[bn * HW + ht * 64 + wt];
            }
            T[co * 33 + wo] = 0.25f * acc;
        }
        __syncthreads();
        for (int it = 0; it < 32; it++) {
            const int l = it * 256 + threadIdx.x;
            const int c2 = l >> 5, w2 = l & 31;
            out[b * CHW + c2 * HW + ho * 64 + hf * 32 + w2] = T[c2 * 33 + w2];
        }
        __syncthreads();
    }
}

// ---------------------------------------------------------------------------
extern "C" void kernel_launch(void* const* d_in, const int* in_sizes, int n_in,
                              void* d_out, int out_size, void* d_ws, size_t ws_size,
                              hipStream_t stream) {
    const float* x        = (const float*)d_in[0];
    const float* spline_w = (const float*)d_in[1];
    const float* scalers  = (const float*)d_in[2];
    const float* ft_w1    = (const float*)d_in[3];
    const float* ft_b1    = (const float*)d_in[4];
    const float* bn_g     = (const float*)d_in[5];
    const float* bn_b     = (const float*)d_in[6];
    const float* bn_m     = (const float*)d_in[7];
    const float* bn_v     = (const float*)d_in[8];
    const float* ft_w2    = (const float*)d_in[9];
    const float* ft_b2    = (const float*)d_in[10];
    const float* ca_w1    = (const float*)d_in[11];
    const float* ca_b1    = (const float*)d_in[12];
    const float* ca_w2    = (const float*)d_in[13];
    const float* ca_b2    = (const float*)d_in[14];
    const float* sa_w     = (const float*)d_in[15];
    const float* sa_b     = (const float*)d_in[16];

    char* p = (char*)d_ws;
    auto alloc = [&](size_t bytes) {
        char* r = p;
        p += (bytes + 255) & ~(size_t)255;
        return r;
    };
    // small buffers (~6.6 MB)
    float* K2      = (float*)alloc(262144 * 4);
    f16*   W1h     = (f16*)alloc(589824 * 2);
    f16*   W1l     = (f16*)alloc(589824 * 2);
    f16*   W2h     = (f16*)alloc(589824 * 2);
    f16*   W2l     = (f16*)alloc(589824 * 2);
    float* weff    = (float*)alloc(1024 * 4);
    float* bnscale = (float*)alloc(256 * 4);
    float* bnbias  = (float*)alloc(256 * 4);
    float* gapb    = (float*)alloc(4096 * 4);
    float* cwb     = (float*)alloc(4096 * 4);
    float* avgm    = (float*)alloc(65536 * 4);
    float* mxm     = (float*)alloc(65536 * 4);
    float* swm     = (float*)alloc(65536 * 4);
    // two large aliased regions, 64 MB each (~134 MB total workspace)
    const size_t HALF = (size_t)16777216 * 2;   // 32 MB
    char* R1 = alloc(2 * HALF);
    char* R2 = alloc(2 * HALF);
    // R1 lifetimes: bufA (decompose out, fp32) -> Y1h/Y1l (conv1 out, conv3 out)
    float* bufA = (float*)R1;
    f16*   Y1h  = (f16*)R1;
    f16*   Y1l  = (f16*)(R1 + HALF);
    // R2 lifetimes: X1h/X1l (conv1 in) -> Y2h/Y2l (conv2 out) -> t2 (fp32 NCHW)
    f16*   X1h  = (f16*)R2;
    f16*   X1l  = (f16*)(R2 + HALF);
    f16*   Y2h  = (f16*)R2;
    f16*   Y2l  = (f16*)(R2 + HALF);
    float* t2   = (float*)R2;

    k2_kernel<<<256, 256, 0, stream>>>(K2);
    wsplit_kernel<<<2304, 256, 0, stream>>>(ft_w1, W1h, W1l);
    wsplit_kernel<<<2304, 256, 0, stream>>>(ft_w2, W2h, W2l);
    small_pre_kernel<<<1, 256, 0, stream>>>(spline_w, scalers, bn_g, bn_b, bn_m,
                                            bn_v, ft_b1, weff, bnscale, bnbias);
    decompose_kernel<<<dim3(8, 256), 256, 0, stream>>>(x, K2, bufA);
    xpose_kernel<<<dim3(128, 16), 256, 0, stream>>>(bufA, X1h, X1l);   // R1 -> R2

    dim3 cgrid(2, 32, 16);
    conv_mfma_kernel<1, 1><<<cgrid, 256, 0, stream>>>(X1h, X1l, W1h, W1l,
                                                      bnscale, bnbias, Y1h, Y1l, nullptr);  // R2->R1
    conv_mfma_kernel<0, 1><<<cgrid, 256, 0, stream>>>(Y1h, Y1l, W2h, W2l,
                                                      nullptr, ft_b2, Y2h, Y2l, nullptr);   // R1->R2
    conv_mfma_kernel<1, 1><<<cgrid, 256, 0, stream>>>(Y2h, Y2l, W1h, W1l,
                                                      bnscale, bnbias, Y1h, Y1l, nullptr);  // R2->R1
    conv_mfma_kernel<0, 0><<<cgrid, 256, 0, stream>>>(Y1h, Y1l, W2h, W2l,
                                                      nullptr, ft_b2, nullptr, nullptr, t2); // R1->R2

    gap_kernel<<<4096, 256, 0, stream>>>(t2, gapb);
    ca_kernel<<<16, 256, 0, stream>>>(gapb, ca_w1, ca_b1, ca_w2, ca_b2, cwb);
    samap_kernel<<<256, 256, 0, stream>>>(t2, cwb, avgm, mxm);
    sw_kernel<<<256, 256, 0, stream>>>(avgm, mxm, sa_w, sa_b, swm);
    fuse_kernel<<<256, 256, 0, stream>>>(t2, cwb, swm, weff, (float*)d_out);
}

// Round 8
// 1070.530 us; speedup vs baseline: 1.4173x; 1.4173x over previous
//
#include <hip/hip_runtime.h>
#include <hip/hip_bf16.h>

// SSAMLayer: decompose GEMM (fp32) -> [xpose to f16 hi/lo] -> 4x conv3x3 via
// MFMA f16 3-product split -> attention tail (fp32) -> fused spline output.
// Conv v4: W in FRAGMENT-MAJOR global layout (coalesced 1KB/instr B-frag
// loads, 4 lines/load, SGPR-foldable offsets); W never touches LDS; one-tap
// register ping-pong prefetch; 2 barriers/chunk. LDS = swizzled A tile only.

#define CHW   1048576   // 256*64*64
#define HW    4096      // 64*64

typedef _Float16 f16;
typedef _Float16 f16x8 __attribute__((ext_vector_type(8)));
typedef float    f32x4 __attribute__((ext_vector_type(4)));

// ---------------------------------------------------------------------------
// K2[c][o], o = n*256+t : irfft-of-sliced-rfft as a per-pixel matrix.
// K_n[t][c] = (1/256)[cos(2pi*s*c/256) + 2*sum_{k=1}^{L-1} cos(2pi*((s+k)c - kt)/256)]
__global__ __launch_bounds__(256) void k2_kernel(float* __restrict__ K2) {
    __shared__ float ctab[256];
    const int c = blockIdx.x;
    const int t = threadIdx.x;
    ctab[t] = cosf((float)t * 0.024543692606170259f);  // 2*pi/256
    __syncthreads();
#pragma unroll
    for (int q = 0; q < 4; q++) {
        const int o = q * 256 + t;
        const int s = q * 32;
        const int L = (q == 3) ? 33 : 32;
        float sum = ctab[(s * c) & 255];
        for (int k = 1; k < L; k++) {
            int m = ((s + k) * c + k * (256 - t)) & 255;
            sum += 2.f * ctab[m];
        }
        K2[c * 1024 + o] = sum * 0.00390625f;
    }
}

// Split conv weights into f16 hi/lo, FRAGMENT-MAJOR layout:
// Wf[tap][chunk(8)][half(2)][ocgrp(16)][lane(64)][8], where lane = icg*16+lrow
// holds W[oc=ocgrp*16+lrow][ic=chunk*32+icg*8+j] (j=0..7). A wave's B-frag for
// (tap,chunk,half,nf) is then base + lane*16B: fully coalesced.
__global__ __launch_bounds__(256) void wsplit_kernel(const float* __restrict__ w,
                                                     f16* __restrict__ Wf) {
    const int tap = blockIdx.x / 16;      // 0..8
    const int ocgrp = blockIdx.x % 16;    // 0..15
    const int l = threadIdx.x & 63;
    const int c2 = threadIdx.x >> 6;      // 0..3
    const int lrow = l & 15, icg = l >> 4;
    const int oc = ocgrp * 16 + lrow;
#pragma unroll
    for (int s = 0; s < 2; ++s) {
        const int cc = c2 + s * 4;        // chunk 0..7
        const int icb = cc * 32 + icg * 8;
        f16x8 hi, lo;
#pragma unroll
        for (int j = 0; j < 8; ++j) {
            float v = w[(oc * 256 + icb + j) * 9 + tap];
            f16 h = (f16)v;
            hi[j] = h;
            lo[j] = (f16)(v - (float)h);
        }
        const size_t base = (((size_t)(tap * 8 + cc) * 2) * 16 + ocgrp) * 512 +
                            (size_t)l * 8;
        *(f16x8*)&Wf[base] = hi;
        *(f16x8*)&Wf[base + 8192] = lo;   // half stride = 16 ocgrp * 512
    }
}

// w_eff[n][c] = sum_j spline_w[n][j][c]*scalers[n][j][c]; BN folded scale/bias.
__global__ __launch_bounds__(256) void small_pre_kernel(
    const float* __restrict__ spw, const float* __restrict__ scl,
    const float* __restrict__ bn_g, const float* __restrict__ bn_b,
    const float* __restrict__ bn_m, const float* __restrict__ bn_v,
    const float* __restrict__ ft_b1, float* __restrict__ weff,
    float* __restrict__ bnscale, float* __restrict__ bnbias) {
    const int c = threadIdx.x;
    const float s = bn_g[c] * rsqrtf(bn_v[c] + 1e-5f);
    bnscale[c] = s;
    bnbias[c] = (ft_b1[c] - bn_m[c]) * s + bn_b[c];
    for (int n = 0; n < 4; n++) {
        float acc = 0.f;
        for (int j = 0; j < 256; j++)
            acc += spw[n * 65536 + j * 256 + c] * scl[n * 65536 + j * 256 + c];
        weff[n * 256 + c] = acc;
    }
}

// xd[b][n][h][w][cc] = sum_c x[b][c][h][w] * K2[c][n*256+cc]   (fp32 GEMM)
__global__ __launch_bounds__(256) void decompose_kernel(const float* __restrict__ x,
                                                        const float* __restrict__ K2,
                                                        float* __restrict__ xd) {
    const int o0 = blockIdx.x * 128;
    const int p0 = blockIdx.y * 64;
    const int b = p0 >> 12;
    const int prow = p0 & 4095;
    const int t = threadIdx.x;
    const int pg = t >> 4, og = t & 15;
    __shared__ float As[16][64];
    __shared__ float Bs[16][128];
    float acc[4][8];
#pragma unroll
    for (int i = 0; i < 4; i++)
#pragma unroll
        for (int j = 0; j < 8; j++) acc[i][j] = 0.f;

    for (int c0 = 0; c0 < 256; c0 += 16) {
#pragma unroll
        for (int i = 0; i < 4; i++) {
            int c = (t >> 6) + i * 4;
            As[c][t & 63] = x[b * CHW + (c0 + c) * HW + prow + (t & 63)];
        }
#pragma unroll
        for (int i = 0; i < 8; i++) {
            int l = i * 256 + t;
            Bs[l >> 7][l & 127] = K2[(c0 + (l >> 7)) * 1024 + o0 + (l & 127)];
        }
        __syncthreads();
#pragma unroll
        for (int k = 0; k < 16; k++) {
            float a[4], bb[8];
            *(float4*)a = *(const float4*)&As[k][pg * 4];
            *(float4*)&bb[0] = *(const float4*)&Bs[k][og * 8];
            *(float4*)&bb[4] = *(const float4*)&Bs[k][og * 8 + 4];
#pragma unroll
            for (int i = 0; i < 4; i++)
#pragma unroll
                for (int j = 0; j < 8; j++) acc[i][j] = fmaf(a[i], bb[j], acc[i][j]);
        }
        __syncthreads();
    }
#pragma unroll
    for (int i = 0; i < 4; i++) {
        const int p = prow + pg * 4 + i;
#pragma unroll
        for (int j = 0; j < 8; j++) {
            const int o = o0 + og * 8 + j;
            const int n = o >> 8, cc = o & 255;
            xd[b * 4194304 + n * CHW + p * 256 + cc] = acc[i][j];
        }
    }
}

// Transpose decompose output (raw reinterpretation) into conv1's A layout:
// X[p'][c'] = bufA[c'*16 + (p'>>8)][p'&255]   (per bn), split f16 hi/lo.
__global__ __launch_bounds__(256) void xpose_kernel(const float* __restrict__ in,
                                                    f16* __restrict__ Xh,
                                                    f16* __restrict__ Xl) {
    const int bn = blockIdx.y;
    const int tid = blockIdx.x;            // 0..127
    const int k = tid & 15;
    const int cc0 = ((tid >> 4) & 1) * 128;
    const int c0p = (tid >> 5) * 64;       // c' tile base
    __shared__ float T[64 * 132];
    const int base = bn * 1048576;
    for (int c = threadIdx.x; c < 2048; c += 256) {   // 8 iters
        int cl = c >> 5;           // c' local 0..63
        int ccq = c & 31;          // cc chunk of 4
        int pd = (c0p + cl) * 16 + k;
        *(float4*)&T[cl * 132 + ccq * 4] =
            *(const float4*)&in[base + pd * 256 + cc0 + ccq * 4];
    }
    __syncthreads();
    for (int m = threadIdx.x; m < 1024; m += 256) {   // 4 iters
        int pl = m >> 3;           // 0..127
        int cq = m & 7;            // c' chunk of 8
        f16x8 hi, lo;
#pragma unroll
        for (int j = 0; j < 8; ++j) {
            float v = T[(cq * 8 + j) * 132 + pl];
            f16 h = (f16)v;
            hi[j] = h;
            lo[j] = (f16)(v - (float)h);
        }
        int pp = k * 256 + cc0 + pl;
        int o = base + pp * 256 + c0p + cq * 8;
        *(f16x8*)&Xh[o] = hi;
        *(f16x8*)&Xl[o] = lo;
    }
}

// ---------------------------------------------------------------------------
// Conv3x3 256->256 via MFMA f16 3-product split, v4 schedule.
// LDS: A tile only, [200 pos][2 half][32 ic], 128B rows, quad ^= pos&7.
// B-fragments: coalesced loads from fragment-major Wf (1KB/instr, 4 lines),
// one-tap-ahead register prefetch (ping-pong bh/bl[2][4]); tap0's loads
// issued at chunk top, hidden under A staging. 2 barriers per chunk.
template <int MODE, int PACKED>
__global__ __launch_bounds__(256, 2) void conv_mfma_kernel(
    const f16* __restrict__ Xh, const f16* __restrict__ Xl,
    const f16* __restrict__ Wf,
    const float* __restrict__ scale, const float* __restrict__ bias,
    f16* __restrict__ Oh, f16* __restrict__ Ol, float* __restrict__ Of) {
    const int oc0 = blockIdx.x * 128;
    const int h0 = (blockIdx.y >> 2) * 8;
    const int w0 = (blockIdx.y & 3) * 16;
    const int bn = blockIdx.z;

    __shared__ __align__(16) f16 smem[16384];   // 32 KB (A: 12800; epi: 16384)
    f16* At = smem;

    const int t = threadIdx.x;
    const int wid = t >> 6, lane = t & 63;
    const int wm = wid >> 1, wn = wid & 1;
    const int lrow = lane & 15, g = lane >> 4;

    // staging decomposition of thread id (16B chunk = 8 f16 of one half)
    const int row_s = t >> 3;            // 0..31 (+32 per iter)
    const int sub_s = t & 7;             // half*4 + icq
    const int half_s = sub_s >> 2, icq_s = sub_s & 3;
    const int swz_s = (sub_s ^ (row_s & 7)) << 3;   // invariant under row+32

    f32x4 acc[4][4];
    const f32x4 z4 = {0.f, 0.f, 0.f, 0.f};
#pragma unroll
    for (int i = 0; i < 4; i++)
#pragma unroll
        for (int j = 0; j < 4; j++) acc[i][j] = z4;

    const int xbase = bn * CHW;

    // fragment-major W base for this wave: ocgrp = oc0/16 + wn*4 (+nf)
    // offsets: tap*131072 + chunk*16384 + half*8192 + nf*512 (+ lane*8)
    const f16* wfb = Wf + ((size_t)((oc0 >> 4) + wn * 4)) * 512 + (size_t)lane * 8;

    f16x8 bh[2][4], bl[2][4];

#pragma unroll 1
    for (int chunk = 0; chunk < 8; ++chunk) {
        const int ic0 = chunk * 32;
        const int cbase = chunk * 16384;
        __syncthreads();   // prev-chunk readers done; safe to overwrite At
        // ---- issue tap0 B prefetch (hides under A staging) ----
#pragma unroll
        for (int nf = 0; nf < 4; ++nf) {
            bh[0][nf] = *(const f16x8*)(wfb + cbase + nf * 512);
            bl[0][nf] = *(const f16x8*)(wfb + cbase + 8192 + nf * 512);
        }
        // ---- stage A: 1600 16B chunks, swizzled ----
        {
            const f16* xs = (half_s ? Xl : Xh) + xbase + ic0 + icq_s * 8;
#pragma unroll
            for (int i = 0; i < 7; ++i) {
                int c = t + i * 256;
                if (c < 1600) {
                    int pos = row_s + i * 32;
                    int r = pos / 20, col = pos - r * 20;
                    int gy = h0 - 1 + r, gx = w0 - 1 + col;
                    f16x8 v = {};
                    if (col < 18 && (unsigned)gy < 64u && (unsigned)gx < 64u)
                        v = *(const f16x8*)(xs + (gy * 64 + gx) * 256);
                    *(f16x8*)&At[pos * 64 + swz_s] = v;
                }
            }
        }
        __syncthreads();
#pragma unroll
        for (int tap = 0; tap < 9; ++tap) {
            const int ky = tap / 3, kx = tap % 3;
            const int pc = tap & 1;
            // ---- prefetch next tap's B frags (consumed next iteration) ----
            if (tap < 8) {
                const int off = (tap + 1) * 131072 + cbase;
#pragma unroll
                for (int nf = 0; nf < 4; ++nf) {
                    bh[pc ^ 1][nf] = *(const f16x8*)(wfb + off + nf * 512);
                    bl[pc ^ 1][nf] = *(const f16x8*)(wfb + off + 8192 + nf * 512);
                }
            }
            // ---- A fragments (conflict-free swizzled reads) + MFMA ----
            f16x8 a_h[4], a_l[4];
#pragma unroll
            for (int mf = 0; mf < 4; ++mf) {
                int pos = (wm * 4 + mf + ky) * 20 + (lrow + kx);
                int p7 = (pos & 7) << 3;
                a_h[mf] = *(const f16x8*)&At[pos * 64 + ((g << 3) ^ p7)];
                a_l[mf] = *(const f16x8*)&At[pos * 64 + (((4 + g) << 3) ^ p7)];
            }
#pragma unroll
            for (int mf = 0; mf < 4; ++mf)
#pragma unroll
                for (int nf = 0; nf < 4; ++nf) {
                    acc[mf][nf] = __builtin_amdgcn_mfma_f32_16x16x32_f16(
                        a_h[mf], bh[pc][nf], acc[mf][nf], 0, 0, 0);
                    acc[mf][nf] = __builtin_amdgcn_mfma_f32_16x16x32_f16(
                        a_h[mf], bl[pc][nf], acc[mf][nf], 0, 0, 0);
                    acc[mf][nf] = __builtin_amdgcn_mfma_f32_16x16x32_f16(
                        a_l[mf], bh[pc][nf], acc[mf][nf], 0, 0, 0);
                }
        }
    }

    // ---- epilogue ----  D frag: col(oc) = lane&15, row(ow) = g*4 + reg
    if (PACKED == 0) {
#pragma unroll
        for (int nf = 0; nf < 4; ++nf) {
            const int oc = oc0 + wn * 64 + nf * 16 + lrow;
            const float sc = (MODE == 1) ? scale[oc] : 1.f;
            const float bi = bias[oc];
#pragma unroll
            for (int mf = 0; mf < 4; ++mf) {
                const int oh = wm * 4 + mf;
                float4 o;
                float* op = &o.x;
#pragma unroll
                for (int j = 0; j < 4; ++j) {
                    float v = acc[mf][nf][j];
                    op[j] = (MODE == 1) ? fmaxf(v * sc + bi, 0.f) : (v + bi);
                }
                *(float4*)&Of[bn * CHW + oc * HW + (h0 + oh) * 64 + w0 + g * 4] = o;
            }
        }
    } else {
        // Th/Tl: [128 px][64 oc] f16, 128B rows, same XOR swizzle.
        f16* Th = smem;
        f16* Tl = smem + 8192;
        for (int half = 0; half < 2; ++half) {
            __syncthreads();
            if (wn == half) {
#pragma unroll
                for (int nf = 0; nf < 4; ++nf) {
                    const int oclb = nf * 16 + lrow;      // 0..63 within half
                    const int oc = oc0 + half * 64 + oclb;
                    const float sc = (MODE == 1) ? scale[oc] : 1.f;
                    const float bi = bias[oc];
#pragma unroll
                    for (int mf = 0; mf < 4; ++mf) {
                        const int pb = (wm * 4 + mf) * 16;
#pragma unroll
                        for (int j = 0; j < 4; ++j) {
                            float v = acc[mf][nf][j];
                            v = (MODE == 1) ? fmaxf(v * sc + bi, 0.f) : (v + bi);
                            f16 hi = (f16)v;
                            int p = pb + g * 4 + j;
                            int idx = p * 64 + (oclb ^ ((p & 7) << 3));
                            Th[idx] = hi;
                            Tl[idx] = (f16)(v - (float)hi);
                        }
                    }
                }
            }
            __syncthreads();
            for (int c = t; c < 1024; c += 256) {
                int p = c >> 3, q = c & 7;
                int src = p * 64 + ((q ^ (p & 7)) << 3);
                int gp = xbase + ((h0 + (p >> 4)) * 64 + w0 + (p & 15)) * 256 +
                         oc0 + half * 64 + q * 8;
                *(f16x8*)&Oh[gp] = *(const f16x8*)&Th[src];
                *(f16x8*)&Ol[gp] = *(const f16x8*)&Tl[src];
            }
        }
    }
}

// ---------------------------------------------------------------------------
__global__ __launch_bounds__(256) void gap_kernel(const float* __restrict__ t2,
                                                  float* __restrict__ gap) {
    const int bc = blockIdx.x;
    const float* p = t2 + bc * HW;
    float s = 0.f;
    for (int i = threadIdx.x; i < 4096; i += 256) s += p[i];
    __shared__ float red[256];
    red[threadIdx.x] = s;
    __syncthreads();
    for (int off = 128; off > 0; off >>= 1) {
        if (threadIdx.x < off) red[threadIdx.x] += red[threadIdx.x + off];
        __syncthreads();
    }
    if (threadIdx.x == 0) gap[bc] = red[0] * (1.f / 4096.f);
}

__global__ __launch_bounds__(256) void ca_kernel(
    const float* __restrict__ gap, const float* __restrict__ w1,
    const float* __restrict__ b1, const float* __restrict__ w2,
    const float* __restrict__ b2, float* __restrict__ cw) {
    const int bn = blockIdx.x;
    const int t = threadIdx.x;
    __shared__ float gsh[256];
    __shared__ float hid[64];
    gsh[t] = gap[bn * 256 + t];
    __syncthreads();
    if (t < 64) {
        float a = b1[t];
        for (int c = 0; c < 256; c++) a += w1[t * 256 + c] * gsh[c];
        hid[t] = 0.5f * a * (1.f + erff(a * 0.70710678118654752f));
    }
    __syncthreads();
    float a = b2[t];
    for (int j = 0; j < 64; j++) a += w2[t * 64 + j] * hid[j];
    cw[bn * 256 + t] = 1.f / (1.f + expf(-a));
}

__global__ __launch_bounds__(256) void samap_kernel(const float* __restrict__ t2,
                                                    const float* __restrict__ cw,
                                                    float* __restrict__ avg,
                                                    float* __restrict__ mx) {
    const int bn = blockIdx.x >> 4;
    const int h = (blockIdx.x & 15) * 4 + (threadIdx.x >> 6);
    const int w = threadIdx.x & 63;
    const float* p = t2 + bn * CHW + h * 64 + w;
    float s = 0.f, m = -3.4e38f;
    for (int c = 0; c < 256; c++) {
        float v = p[c * HW] * cw[bn * 256 + c];
        s += v;
        m = fmaxf(m, v);
    }
    avg[bn * HW + h * 64 + w] = s * (1.f / 256.f);
    mx[bn * HW + h * 64 + w] = m;
}

__global__ __launch_bounds__(256) void sw_kernel(const float* __restrict__ avg,
                                                 const float* __restrict__ mx,
                                                 const float* __restrict__ saw,
                                                 const float* __restrict__ sab,
                                                 float* __restrict__ sw) {
    const int bn = blockIdx.x >> 4;
    const int h = (blockIdx.x & 15) * 4 + (threadIdx.x >> 6);
    const int w = threadIdx.x & 63;
    float a = sab[0];
#pragma unroll
    for (int ky = 0; ky < 3; ky++) {
        int y = h + ky - 1;
        if ((unsigned)y >= 64u) continue;
#pragma unroll
        for (int kx = 0; kx < 3; kx++) {
            int x = w + kx - 1;
            if ((unsigned)x >= 64u) continue;
            int idx = bn * HW + y * 64 + x;
            a += saw[ky * 3 + kx] * avg[idx] + saw[9 + ky * 3 + kx] * mx[idx];
        }
    }
    sw[bn * HW + h * 64 + w] = 1.f / (1.f + expf(-a));
}

__global__ __launch_bounds__(256) void fuse_kernel(const float* __restrict__ t2,
                                                   const float* __restrict__ cw,
                                                   const float* __restrict__ sw,
                                                   const float* __restrict__ weff,
                                                   float* __restrict__ out) {
    const int b = blockIdx.x >> 6;
    const int ho = blockIdx.x & 63;
    const int co = threadIdx.x;
    __shared__ float T[256 * 33];
    float we[4];
#pragma unroll
    for (int n = 0; n < 4; n++) we[n] = weff[n * 256 + co];

    for (int hf = 0; hf < 2; hf++) {
        for (int wo = 0; wo < 32; wo++) {
            const int o = ho * 16384 + (hf * 32 + wo) * 256 + co;
            const int ct = o >> 12;
            const int ht = (o >> 6) & 63;
            const int wt = o & 63;
            float acc = 0.f;
#pragma unroll
            for (int n = 0; n < 4; n++) {
                const int bn = b * 4 + n;
                acc += we[n] * t2[bn * CHW + o] * cw[bn * 256 + ct] *
                       sw[bn * HW + ht * 64 + wt];
            }
            T[co * 33 + wo] = 0.25f * acc;
        }
        __syncthreads();
        for (int it = 0; it < 32; it++) {
            const int l = it * 256 + threadIdx.x;
            const int c2 = l >> 5, w2 = l & 31;
            out[b * CHW + c2 * HW + ho * 64 + hf * 32 + w2] = T[c2 * 33 + w2];
        }
        __syncthreads();
    }
}

// ---------------------------------------------------------------------------
extern "C" void kernel_launch(void* const* d_in, const int* in_sizes, int n_in,
                              void* d_out, int out_size, void* d_ws, size_t ws_size,
                              hipStream_t stream) {
    const float* x        = (const float*)d_in[0];
    const float* spline_w = (const float*)d_in[1];
    const float* scalers  = (const float*)d_in[2];
    const float* ft_w1    = (const float*)d_in[3];
    const float* ft_b1    = (const float*)d_in[4];
    const float* bn_g     = (const float*)d_in[5];
    const float* bn_b     = (const float*)d_in[6];
    const float* bn_m     = (const float*)d_in[7];
    const float* bn_v     = (const float*)d_in[8];
    const float* ft_w2    = (const float*)d_in[9];
    const float* ft_b2    = (const float*)d_in[10];
    const float* ca_w1    = (const float*)d_in[11];
    const float* ca_b1    = (const float*)d_in[12];
    const float* ca_w2    = (const float*)d_in[13];
    const float* ca_b2    = (const float*)d_in[14];
    const float* sa_w     = (const float*)d_in[15];
    const float* sa_b     = (const float*)d_in[16];

    char* p = (char*)d_ws;
    auto alloc = [&](size_t bytes) {
        char* r = p;
        p += (bytes + 255) & ~(size_t)255;
        return r;
    };
    // small buffers (~6.6 MB)
    float* K2      = (float*)alloc(262144 * 4);
    f16*   W1f     = (f16*)alloc((size_t)1179648 * 2);   // frag-major hi+lo
    f16*   W2f     = (f16*)alloc((size_t)1179648 * 2);
    float* weff    = (float*)alloc(1024 * 4);
    float* bnscale = (float*)alloc(256 * 4);
    float* bnbias  = (float*)alloc(256 * 4);
    float* gapb    = (float*)alloc(4096 * 4);
    float* cwb     = (float*)alloc(4096 * 4);
    float* avgm    = (float*)alloc(65536 * 4);
    float* mxm     = (float*)alloc(65536 * 4);
    float* swm     = (float*)alloc(65536 * 4);
    // two large aliased regions, 64 MB each (~134 MB total workspace)
    const size_t HALF = (size_t)16777216 * 2;   // 32 MB
    char* R1 = alloc(2 * HALF);
    char* R2 = alloc(2 * HALF);
    // R1 lifetimes: bufA (decompose out, fp32) -> Y1h/Y1l (conv1 out, conv3 out)
    float* bufA = (float*)R1;
    f16*   Y1h  = (f16*)R1;
    f16*   Y1l  = (f16*)(R1 + HALF);
    // R2 lifetimes: X1h/X1l (conv1 in) -> Y2h/Y2l (conv2 out) -> t2 (fp32 NCHW)
    f16*   X1h  = (f16*)R2;
    f16*   X1l  = (f16*)(R2 + HALF);
    f16*   Y2h  = (f16*)R2;
    f16*   Y2l  = (f16*)(R2 + HALF);
    float* t2   = (float*)R2;

    k2_kernel<<<256, 256, 0, stream>>>(K2);
    wsplit_kernel<<<144, 256, 0, stream>>>(ft_w1, W1f);
    wsplit_kernel<<<144, 256, 0, stream>>>(ft_w2, W2f);
    small_pre_kernel<<<1, 256, 0, stream>>>(spline_w, scalers, bn_g, bn_b, bn_m,
                                            bn_v, ft_b1, weff, bnscale, bnbias);
    decompose_kernel<<<dim3(8, 256), 256, 0, stream>>>(x, K2, bufA);
    xpose_kernel<<<dim3(128, 16), 256, 0, stream>>>(bufA, X1h, X1l);   // R1 -> R2

    dim3 cgrid(2, 32, 16);
    conv_mfma_kernel<1, 1><<<cgrid, 256, 0, stream>>>(X1h, X1l, W1f,
                                                      bnscale, bnbias, Y1h, Y1l, nullptr);  // R2->R1
    conv_mfma_kernel<0, 1><<<cgrid, 256, 0, stream>>>(Y1h, Y1l, W2f,
                                                      nullptr, ft_b2, Y2h, Y2l, nullptr);   // R1->R2
    conv_mfma_kernel<1, 1><<<cgrid, 256, 0, stream>>>(Y2h, Y2l, W1f,
                                                      bnscale, bnbias, Y1h, Y1l, nullptr);  // R2->R1
    conv_mfma_kernel<0, 0><<<cgrid, 256, 0, stream>>>(Y1h, Y1l, W2f,
                                                      nullptr, ft_b2, nullptr, nullptr, t2); // R1->R2

    gap_kernel<<<4096, 256, 0, stream>>>(t2, gapb);
    ca_kernel<<<16, 256, 0, stream>>>(gapb, ca_w1, ca_b1, ca_w2, ca_b2, cwb);
    samap_kernel<<<256, 256, 0, stream>>>(t2, cwb, avgm, mxm);
    sw_kernel<<<256, 256, 0, stream>>>(avgm, mxm, sa_w, sa_b, swm);
    fuse_kernel<<<256, 256, 0, stream>>>(t2, cwb, swm, weff, (float*)d_out);
}